// Round 11
// baseline (206.444 us; speedup 1.0000x reference)
//
#include <hip/hip_runtime.h>
#include <math.h>

#define NB 4
#define NC 4
#define NF 257
#define NFR 1024
#define NTOT (NB * NC * NF * NFR)
#define NBC (NB * NC)
#define EPSV 1e-3f
#define EPS_MODEL 1e-5f
#define NCHUNK 32

typedef float v2f __attribute__((ext_vector_type(2)));

// Forced VOP3P packed-f32 ops (backend scalarizes <2 x float> arithmetic).
__device__ __forceinline__ v2f pk_mul(v2f a, v2f b) {
  v2f d; asm("v_pk_mul_f32 %0, %1, %2" : "=v"(d) : "v"(a), "v"(b)); return d;
}
__device__ __forceinline__ v2f pk_fma(v2f a, v2f b, v2f c) {  // a*b + c
  v2f d; asm("v_pk_fma_f32 %0, %1, %2, %3" : "=v"(d) : "v"(a), "v"(b), "v"(c)); return d;
}
__device__ __forceinline__ v2f pk_fnma(v2f a, v2f b, v2f c) { // c - a*b
  v2f d; asm("v_pk_fma_f32 %0, %1, %2, %3 neg_lo:[1,0,0] neg_hi:[1,0,0]"
             : "=v"(d) : "v"(a), "v"(b), "v"(c));
  return d;
}
__device__ __forceinline__ v2f splat2(float x) { return (v2f){x, x}; }

// Module-scope scratch: allocated at load, graph-capture safe, fully
// rewritten every call.
__device__ float g_Spart[NCHUNK * NBC * NFR];  // partial column sums
__device__ float g_S[NBC * NFR];               // S[b,c,n] = sum_f |X[b,c,f,n]|^2
__device__ float g_gP[96];                     // g_e, P_e per (b,c), e=0..2

// Wave-wide sum via DPP (VALU pipe, no LDS traffic). Lane 63 holds the sum.
__device__ __forceinline__ float dpp_red_sum(float v) {
  v += __int_as_float(__builtin_amdgcn_update_dpp(0, __float_as_int(v), 0x111, 0xf, 0xf, true)); // row_shr:1
  v += __int_as_float(__builtin_amdgcn_update_dpp(0, __float_as_int(v), 0x112, 0xf, 0xf, true)); // row_shr:2
  v += __int_as_float(__builtin_amdgcn_update_dpp(0, __float_as_int(v), 0x114, 0xf, 0xf, true)); // row_shr:4
  v += __int_as_float(__builtin_amdgcn_update_dpp(0, __float_as_int(v), 0x118, 0xf, 0xf, true)); // row_shr:8
  v += __int_as_float(__builtin_amdgcn_update_dpp(0, __float_as_int(v), 0x142, 0xa, 0xf, true)); // row_bcast:15
  v += __int_as_float(__builtin_amdgcn_update_dpp(0, __float_as_int(v), 0x143, 0xc, 0xf, true)); // row_bcast:31
  return v;
}

// ---------------------------------------------------------------------------
// K1: partial column sums, float4-vectorized, 512 blocks (full GPU).
// ---------------------------------------------------------------------------
__global__ __launch_bounds__(256) void k_colsum(const float* __restrict__ Xr,
                                                const float* __restrict__ Xi) {
  int u = blockIdx.x * 256 + threadIdx.x;  // bc*256 + q
  int fc = blockIdx.y;
  int f0 = fc * 9;
  int f1 = f0 + 9; if (f1 > NF) f1 = NF;
  int bc = u >> 8, q = u & 255;
  float4 s = make_float4(0.f, 0.f, 0.f, 0.f);
  for (int f = f0; f < f1; ++f) {
    float4 a = reinterpret_cast<const float4*>(Xr + (bc * NF + f) * NFR)[q];
    float4 b = reinterpret_cast<const float4*>(Xi + (bc * NF + f) * NFR)[q];
    s.x += a.x * a.x + b.x * b.x;
    s.y += a.y * a.y + b.y * b.y;
    s.z += a.z * a.z + b.z * b.z;
    s.w += a.w * a.w + b.w * b.w;
  }
  reinterpret_cast<float4*>(g_Spart + fc * (NBC * NFR) + bc * NFR)[q] = s;
}

// ---------------------------------------------------------------------------
// K2 (fused): reduce 32 partials -> g_S; block-reduce to s0; g_e/P_e table.
// ---------------------------------------------------------------------------
__global__ __launch_bounds__(256) void k_redgp() {
  int bc = blockIdx.x, tid = threadIdx.x;
  float4 s = make_float4(0.f, 0.f, 0.f, 0.f);
#pragma unroll
  for (int fc = 0; fc < NCHUNK; ++fc) {
    float4 a = reinterpret_cast<const float4*>(g_Spart + fc * (NBC * NFR) + bc * NFR)[tid];
    s.x += a.x; s.y += a.y; s.z += a.z; s.w += a.w;
  }
  reinterpret_cast<float4*>(g_S + bc * NFR)[tid] = s;
  float p = dpp_red_sum(s.x + s.y + s.z + s.w);
  __shared__ float r[4];
  if ((tid & 63) == 63) r[tid >> 6] = p;
  __syncthreads();
  if (tid == 0) {
    float s0 = (r[0] + r[1] + r[2] + r[3]) / (float)(NF * NFR);
    float P = 1.f;
#pragma unroll
    for (int e = 0; e < 3; ++e) {
      float g = fmaxf(s0 / P, 1e-5f);
      g_gP[e * 32 + bc] = g;
      g_gP[e * 32 + 16 + bc] = P;
      P *= g;
    }
  }
}

// Block-level reduction of 12 partials, 2-wave version: DPP within wave,
// one barrier, b128 LDS round-trip, double-buffered via `buf`.
__device__ __forceinline__ void block_reduce12(float* __restrict__ p,
                                               float (*red)[2][12], int buf,
                                               int lane, int wvid,
                                               float* __restrict__ s) {
#pragma unroll
  for (int k = 0; k < 12; ++k) p[k] = dpp_red_sum(p[k]);
  if (lane == 63) {
    float4* dst = reinterpret_cast<float4*>(&red[buf][wvid][0]);
    dst[0] = make_float4(p[0], p[1], p[2], p[3]);
    dst[1] = make_float4(p[4], p[5], p[6], p[7]);
    dst[2] = make_float4(p[8], p[9], p[10], p[11]);
  }
  __syncthreads();
  const float4* r = reinterpret_cast<const float4*>(&red[buf][0][0]);
#pragma unroll
  for (int k = 0; k < 3; ++k) {
    float4 a = r[k], b = r[3 + k];
    s[4 * k + 0] = a.x + b.x;
    s[4 * k + 1] = a.y + b.y;
    s[4 * k + 2] = a.z + b.z;
    s[4 * k + 3] = a.w + b.w;
  }
}

// ---------------------------------------------------------------------------
// Main: one block per (b,f), 128 threads (2 waves), 8 frames/thread as
// 4x v2f pairs; hot FMA streams forced to v_pk_*_f32 via inline asm.
// w_e = K_e * rsq(S), K_e = 0.5*g_e*sqrt(P_e) (eps clamp unreachable here).
// ---------------------------------------------------------------------------
__global__ __launch_bounds__(128, 2) void k_main(const float* __restrict__ Xr,
                                                 const float* __restrict__ Xi,
                                                 float* __restrict__ out, int nout) {
  const int blk = blockIdx.x;
  const int b = blk / NF, f = blk % NF;
  const int tid = threadIdx.x;            // 0..127
  const int lane = tid & 63, wvid = tid >> 6;
  const float invN = 1.f / (float)NFR;

  __shared__ float red[2][2][12];
  __shared__ float Wre[NC][NC], Wim[NC][NC];
  __shared__ float abc[8];

  v2f xcr[NC][4], xci[NC][4];
  int rowbase[NC];
#pragma unroll
  for (int c = 0; c < NC; ++c) {
    rowbase[c] = ((b * NC + c) * NF + f) * NFR;
    const float4* pr = reinterpret_cast<const float4*>(Xr + rowbase[c]);
    const float4* pi = reinterpret_cast<const float4*>(Xi + rowbase[c]);
    float4 a0 = pr[2 * tid], a1 = pr[2 * tid + 1];
    float4 b0 = pi[2 * tid], b1 = pi[2 * tid + 1];
    xcr[c][0] = (v2f){a0.x, a0.y}; xcr[c][1] = (v2f){a0.z, a0.w};
    xcr[c][2] = (v2f){a1.x, a1.y}; xcr[c][3] = (v2f){a1.z, a1.w};
    xci[c][0] = (v2f){b0.x, b0.y}; xci[c][1] = (v2f){b0.z, b0.w};
    xci[c][2] = (v2f){b1.x, b1.y}; xci[c][3] = (v2f){b1.z, b1.w};
  }
  if (tid < 16) {
    Wre[tid >> 2][tid & 3] = ((tid >> 2) == (tid & 3)) ? 1.f : 0.f;
    Wim[tid >> 2][tid & 3] = 0.f;
  }
  // W-init visibility to thread 0: ordered by the first sweep's barrier.

  // rsq(S) once; per-epoch weights are one pk-mul per v2f pair.
  v2f rsqS[NC][4];
#pragma unroll
  for (int c = 0; c < NC; ++c) {
    const float4* ps = reinterpret_cast<const float4*>(g_S + (b * NC + c) * NFR);
    float4 S0 = ps[2 * tid], S1 = ps[2 * tid + 1];
    rsqS[c][0] = (v2f){__builtin_amdgcn_rsqf(S0.x), __builtin_amdgcn_rsqf(S0.y)};
    rsqS[c][1] = (v2f){__builtin_amdgcn_rsqf(S0.z), __builtin_amdgcn_rsqf(S0.w)};
    rsqS[c][2] = (v2f){__builtin_amdgcn_rsqf(S1.x), __builtin_amdgcn_rsqf(S1.y)};
    rsqS[c][3] = (v2f){__builtin_amdgcn_rsqf(S1.z), __builtin_amdgcn_rsqf(S1.w)};
  }

  v2f w2[NC][4];
  int buf = 0;

  for (int e = 0; e < 3; ++e) {
    // ---- per-epoch weights: w = K * rsq(S), K = 0.5*g*sqrt(P) ----
#pragma unroll
    for (int c = 0; c < NC; ++c) {
      float g = g_gP[e * 32 + b * NC + c];
      float P = g_gP[e * 32 + 16 + b * NC + c];
      v2f Kp = splat2(0.5f * g * __builtin_amdgcn_sqrtf(P));
#pragma unroll
      for (int h = 0; h < 4; ++h) w2[c][h] = pk_mul(Kp, rsqS[c][h]);
    }

    // ================= type-1 sweeps =================
    for (int src = 0; src < NC; ++src) {
      v2f p2[12];
#pragma unroll
      for (int k = 0; k < 12; ++k) p2[k] = (v2f){0.f, 0.f};
#pragma unroll
      for (int h = 0; h < 4; ++h) {
        v2f xsr = xcr[src][h], xsi = xci[src][h];
        v2f msq = pk_fma(xsi, xsi, pk_mul(xsr, xsr));
#pragma unroll
        for (int c = 0; c < NC; ++c) {
          v2f wv = w2[c][h];
          v2f t1 = pk_fma(xci[c][h], xsi, pk_mul(xcr[c][h], xsr));
          p2[c] = pk_fma(wv, t1, p2[c]);
          v2f t2 = pk_fnma(xcr[c][h], xsi, pk_mul(xci[c][h], xsr));
          p2[4 + c] = pk_fma(wv, t2, p2[4 + c]);
          p2[8 + c] = pk_fma(wv, msq, p2[8 + c]);
        }
      }
      float p[12];
#pragma unroll
      for (int k = 0; k < 12; ++k) p[k] = p2[k].x + p2[k].y;
      float s12[12];
      block_reduce12(p, red, buf, lane, wvid, s12);
      buf ^= 1;

      float vr[NC], vi[NC];
#pragma unroll
      for (int c = 0; c < NC; ++c) {
        float den = fmaxf(s12[8 + c] * invN, EPSV);
        if (c == src) {
          vr[c] = 1.f - __builtin_amdgcn_rsqf(den);
          vi[c] = 0.f;
        } else {
          float sc = invN * __builtin_amdgcn_rcpf(den);
          vr[c] = s12[c] * sc;
          vi[c] = s12[4 + c] * sc;
        }
      }
      v2f vrp[NC], vip[NC];
#pragma unroll
      for (int c = 0; c < NC; ++c) { vrp[c] = splat2(vr[c]); vip[c] = splat2(vi[c]); }
#pragma unroll
      for (int h = 0; h < 4; ++h) {
        v2f xsr = xcr[src][h], xsi = xci[src][h];
#pragma unroll
        for (int c = 0; c < NC; ++c) {
          xcr[c][h] = pk_fma(xsi, vip[c], pk_fnma(xsr, vrp[c], xcr[c][h]));
          xci[c][h] = pk_fnma(xsr, vip[c], pk_fnma(xsi, vrp[c], xci[c][h]));
        }
      }
      if (tid == 0) {
#pragma unroll
        for (int jj = 0; jj < NC; ++jj) {
          float wsr = Wre[src][jj], wsi = Wim[src][jj];
#pragma unroll
          for (int c = 0; c < NC; ++c) {
            Wre[c][jj] -= vr[c] * wsr - vi[c] * wsi;
            Wim[c][jj] -= vr[c] * wsi + vi[c] * wsr;
          }
        }
      }
    }

    // ================= type-2 sweeps =================
    for (int src = 0; src < NC; ++src) {
      const float4* pr = reinterpret_cast<const float4*>(Xr + rowbase[src]);
      const float4* pi = reinterpret_cast<const float4*>(Xi + rowbase[src]);
      // 9-frame window [8t-3 .. 8t+5] of ORIGINAL X serves both taps.
      float4 A4r = make_float4(0.f, 0.f, 0.f, 0.f), A4i = A4r;
      if (tid > 0) { A4r = pr[2 * tid - 1]; A4i = pi[2 * tid - 1]; }
      float4 B4r = pr[2 * tid], B4i = pi[2 * tid];
      float4 C4r = pr[2 * tid + 1], C4i = pi[2 * tid + 1];
      float wr[9] = {A4r.y, A4r.z, A4r.w, B4r.x, B4r.y, B4r.z, B4r.w, C4r.x, C4r.y};
      float wi[9] = {A4i.y, A4i.z, A4i.w, B4i.x, B4i.y, B4i.z, B4i.w, C4i.x, C4i.y};
      for (int tap = 0; tap < 2; ++tap) {
        v2f xs_r[4], xs_i[4];
#pragma unroll
        for (int h = 0; h < 4; ++h) {
          xs_r[h] = (v2f){wr[tap + 2 * h], wr[tap + 2 * h + 1]};
          xs_i[h] = (v2f){wi[tap + 2 * h], wi[tap + 2 * h + 1]};
        }
        v2f p2[12];
#pragma unroll
        for (int k = 0; k < 12; ++k) p2[k] = (v2f){0.f, 0.f};
#pragma unroll
        for (int h = 0; h < 4; ++h) {
          v2f xsr = xs_r[h], xsi = xs_i[h];
          v2f msq = pk_fma(xsi, xsi, pk_mul(xsr, xsr));
#pragma unroll
          for (int c = 0; c < NC; ++c) {
            v2f wv = w2[c][h];
            v2f t1 = pk_fma(xci[c][h], xsi, pk_mul(xcr[c][h], xsr));
            p2[c] = pk_fma(wv, t1, p2[c]);
            v2f t2 = pk_fnma(xcr[c][h], xsi, pk_mul(xci[c][h], xsr));
            p2[4 + c] = pk_fma(wv, t2, p2[4 + c]);
            p2[8 + c] = pk_fma(wv, msq, p2[8 + c]);
          }
        }
        float p[12];
#pragma unroll
        for (int k = 0; k < 12; ++k) p[k] = p2[k].x + p2[k].y;
        float s12[12];
        block_reduce12(p, red, buf, lane, wvid, s12);
        buf ^= 1;

        float vr[NC], vi[NC];
#pragma unroll
        for (int c = 0; c < NC; ++c) {
          float den = fmaxf(s12[8 + c], EPSV);  // SUM, not mean
          float sc = invN * __builtin_amdgcn_rcpf(den);
          vr[c] = s12[c] * sc;
          vi[c] = s12[4 + c] * sc;
        }
        v2f vrp[NC], vip[NC];
#pragma unroll
        for (int c = 0; c < NC; ++c) { vrp[c] = splat2(vr[c]); vip[c] = splat2(vi[c]); }
#pragma unroll
        for (int h = 0; h < 4; ++h) {
          v2f xsr = xs_r[h], xsi = xs_i[h];
#pragma unroll
          for (int c = 0; c < NC; ++c) {
            xcr[c][h] = pk_fma(xsi, vip[c], pk_fnma(xsr, vrp[c], xcr[c][h]));
            xci[c][h] = pk_fnma(xsr, vip[c], pk_fnma(xsi, vrp[c], xci[c][h]));
          }
        }
      }
    }
  }  // epochs

  // ---- solve W^T a = e1 (4x4 complex, partial pivoting), A[i][j] = W[j][i] ----
  __syncthreads();
  if (tid == 0) {
    float Ar[4][4], Ai[4][4];
    float br[4] = {1.f, 0.f, 0.f, 0.f}, bi[4] = {0.f, 0.f, 0.f, 0.f};
#pragma unroll
    for (int i = 0; i < 4; ++i)
#pragma unroll
      for (int j = 0; j < 4; ++j) {
        Ar[i][j] = Wre[j][i];
        Ai[i][j] = Wim[j][i];
      }
    for (int k = 0; k < 4; ++k) {
      int piv = k;
      float best = Ar[k][k] * Ar[k][k] + Ai[k][k] * Ai[k][k];
      for (int i = k + 1; i < 4; ++i) {
        float m = Ar[i][k] * Ar[i][k] + Ai[i][k] * Ai[i][k];
        if (m > best) { best = m; piv = i; }
      }
      if (piv != k) {
        for (int j = 0; j < 4; ++j) {
          float t = Ar[k][j]; Ar[k][j] = Ar[piv][j]; Ar[piv][j] = t;
          t = Ai[k][j]; Ai[k][j] = Ai[piv][j]; Ai[piv][j] = t;
        }
        float t = br[k]; br[k] = br[piv]; br[piv] = t;
        t = bi[k]; bi[k] = bi[piv]; bi[piv] = t;
      }
      float dr = Ar[k][k], di = Ai[k][k];
      float inv = 1.f / (dr * dr + di * di);
      for (int i = k + 1; i < 4; ++i) {
        float fr = (Ar[i][k] * dr + Ai[i][k] * di) * inv;
        float fi = (Ai[i][k] * dr - Ar[i][k] * di) * inv;
        for (int j = k; j < 4; ++j) {
          Ar[i][j] -= fr * Ar[k][j] - fi * Ai[k][j];
          Ai[i][j] -= fr * Ai[k][j] + fi * Ar[k][j];
        }
        br[i] -= fr * br[k] - fi * bi[k];
        bi[i] -= fr * bi[k] + fi * br[k];
      }
    }
    float ar[4], ai[4];
    for (int k = 3; k >= 0; --k) {
      float sr = br[k], si = bi[k];
      for (int j = k + 1; j < 4; ++j) {
        sr -= Ar[k][j] * ar[j] - Ai[k][j] * ai[j];
        si -= Ar[k][j] * ai[j] + Ai[k][j] * ar[j];
      }
      float dr = Ar[k][k], di = Ai[k][k];
      float inv = 1.f / (dr * dr + di * di);
      ar[k] = (sr * dr + si * di) * inv;
      ai[k] = (si * dr - sr * di) * inv;
    }
#pragma unroll
    for (int c = 0; c < 4; ++c) { abc[c] = ar[c]; abc[4 + c] = ai[c]; }
  }
  __syncthreads();

  // ---- output: real(Xc * a), 2x float4 per (c, thread), bounds-guarded ----
#pragma unroll
  for (int c = 0; c < NC; ++c) {
    float ar = abc[c], ai2 = abc[4 + c];
    if (rowbase[c] + 8 * tid + 7 < nout) {
      float4* po = reinterpret_cast<float4*>(out + rowbase[c]);
      v2f o0 = xcr[c][0] * ar - xci[c][0] * ai2;
      v2f o1 = xcr[c][1] * ar - xci[c][1] * ai2;
      v2f o2 = xcr[c][2] * ar - xci[c][2] * ai2;
      v2f o3 = xcr[c][3] * ar - xci[c][3] * ai2;
      po[2 * tid]     = make_float4(o0.x, o0.y, o1.x, o1.y);
      po[2 * tid + 1] = make_float4(o2.x, o2.y, o3.x, o3.y);
    }
  }
}

// ---------------------------------------------------------------------------
extern "C" void kernel_launch(void* const* d_in, const int* in_sizes, int n_in,
                              void* d_out, int out_size, void* d_ws, size_t ws_size,
                              hipStream_t stream) {
  const float* Xr = (const float*)d_in[0];
  const float* Xi = (const float*)d_in[1];
  float* out = (float*)d_out;

  dim3 g1(16, NCHUNK);
  k_colsum<<<g1, 256, 0, stream>>>(Xr, Xi);
  k_redgp<<<16, 256, 0, stream>>>();
  k_main<<<NB * NF, 128, 0, stream>>>(Xr, Xi, out, out_size);
}

// Round 12
// 201.525 us; speedup vs baseline: 1.0244x; 1.0244x over previous
//
#include <hip/hip_runtime.h>
#include <math.h>

#define NB 4
#define NC 4
#define NF 257
#define NFR 1024
#define NTOT (NB * NC * NF * NFR)
#define NBC (NB * NC)
#define EPSV 1e-3f
#define EPS_MODEL 1e-5f
#define NCHUNK 32

typedef float v2f __attribute__((ext_vector_type(2)));

// Forced VOP3P packed-f32 ops — used ONLY in the accumulate loops (largest
// instruction stream). Round 11 used these everywhere + a 32-reg precompute
// and fragmented the register allocator into ~90 MB of spills.
__device__ __forceinline__ v2f pk_mul(v2f a, v2f b) {
  v2f d; asm("v_pk_mul_f32 %0, %1, %2" : "=v"(d) : "v"(a), "v"(b)); return d;
}
__device__ __forceinline__ v2f pk_fma(v2f a, v2f b, v2f c) {  // a*b + c
  v2f d; asm("v_pk_fma_f32 %0, %1, %2, %3" : "=v"(d) : "v"(a), "v"(b), "v"(c)); return d;
}
__device__ __forceinline__ v2f pk_fnma(v2f a, v2f b, v2f c) { // c - a*b
  v2f d; asm("v_pk_fma_f32 %0, %1, %2, %3 neg_lo:[1,0,0] neg_hi:[1,0,0]"
             : "=v"(d) : "v"(a), "v"(b), "v"(c));
  return d;
}

// Module-scope scratch: allocated at load, graph-capture safe, fully
// rewritten every call.
__device__ float g_Spart[NCHUNK * NBC * NFR];  // partial column sums
__device__ float g_S[NBC * NFR];               // S[b,c,n] = sum_f |X[b,c,f,n]|^2
__device__ float g_gP[96];                     // g_e, P_e per (b,c), e=0..2

// Wave-wide sum via DPP (VALU pipe, no LDS traffic). Lane 63 holds the sum.
__device__ __forceinline__ float dpp_red_sum(float v) {
  v += __int_as_float(__builtin_amdgcn_update_dpp(0, __float_as_int(v), 0x111, 0xf, 0xf, true)); // row_shr:1
  v += __int_as_float(__builtin_amdgcn_update_dpp(0, __float_as_int(v), 0x112, 0xf, 0xf, true)); // row_shr:2
  v += __int_as_float(__builtin_amdgcn_update_dpp(0, __float_as_int(v), 0x114, 0xf, 0xf, true)); // row_shr:4
  v += __int_as_float(__builtin_amdgcn_update_dpp(0, __float_as_int(v), 0x118, 0xf, 0xf, true)); // row_shr:8
  v += __int_as_float(__builtin_amdgcn_update_dpp(0, __float_as_int(v), 0x142, 0xa, 0xf, true)); // row_bcast:15
  v += __int_as_float(__builtin_amdgcn_update_dpp(0, __float_as_int(v), 0x143, 0xc, 0xf, true)); // row_bcast:31
  return v;
}

// ---------------------------------------------------------------------------
// K1: partial column sums, float4-vectorized, 512 blocks (full GPU).
// ---------------------------------------------------------------------------
__global__ __launch_bounds__(256) void k_colsum(const float* __restrict__ Xr,
                                                const float* __restrict__ Xi) {
  int u = blockIdx.x * 256 + threadIdx.x;  // bc*256 + q
  int fc = blockIdx.y;
  int f0 = fc * 9;
  int f1 = f0 + 9; if (f1 > NF) f1 = NF;
  int bc = u >> 8, q = u & 255;
  float4 s = make_float4(0.f, 0.f, 0.f, 0.f);
  for (int f = f0; f < f1; ++f) {
    float4 a = reinterpret_cast<const float4*>(Xr + (bc * NF + f) * NFR)[q];
    float4 b = reinterpret_cast<const float4*>(Xi + (bc * NF + f) * NFR)[q];
    s.x += a.x * a.x + b.x * b.x;
    s.y += a.y * a.y + b.y * b.y;
    s.z += a.z * a.z + b.z * b.z;
    s.w += a.w * a.w + b.w * b.w;
  }
  reinterpret_cast<float4*>(g_Spart + fc * (NBC * NFR) + bc * NFR)[q] = s;
}

// ---------------------------------------------------------------------------
// K2 (fused): reduce 32 partials -> g_S; block-reduce to s0; g_e/P_e table.
// ---------------------------------------------------------------------------
__global__ __launch_bounds__(256) void k_redgp() {
  int bc = blockIdx.x, tid = threadIdx.x;
  float4 s = make_float4(0.f, 0.f, 0.f, 0.f);
#pragma unroll
  for (int fc = 0; fc < NCHUNK; ++fc) {
    float4 a = reinterpret_cast<const float4*>(g_Spart + fc * (NBC * NFR) + bc * NFR)[tid];
    s.x += a.x; s.y += a.y; s.z += a.z; s.w += a.w;
  }
  reinterpret_cast<float4*>(g_S + bc * NFR)[tid] = s;
  float p = dpp_red_sum(s.x + s.y + s.z + s.w);
  __shared__ float r[4];
  if ((tid & 63) == 63) r[tid >> 6] = p;
  __syncthreads();
  if (tid == 0) {
    float s0 = (r[0] + r[1] + r[2] + r[3]) / (float)(NF * NFR);
    float P = 1.f;
#pragma unroll
    for (int e = 0; e < 3; ++e) {
      float g = fmaxf(s0 / P, 1e-5f);
      g_gP[e * 32 + bc] = g;
      g_gP[e * 32 + 16 + bc] = P;
      P *= g;
    }
  }
}

// Block-level reduction of 12 partials, 2-wave version: DPP within wave,
// one barrier, b128 LDS round-trip, double-buffered via `buf`.
__device__ __forceinline__ void block_reduce12(float* __restrict__ p,
                                               float (*red)[2][12], int buf,
                                               int lane, int wvid,
                                               float* __restrict__ s) {
#pragma unroll
  for (int k = 0; k < 12; ++k) p[k] = dpp_red_sum(p[k]);
  if (lane == 63) {
    float4* dst = reinterpret_cast<float4*>(&red[buf][wvid][0]);
    dst[0] = make_float4(p[0], p[1], p[2], p[3]);
    dst[1] = make_float4(p[4], p[5], p[6], p[7]);
    dst[2] = make_float4(p[8], p[9], p[10], p[11]);
  }
  __syncthreads();
  const float4* r = reinterpret_cast<const float4*>(&red[buf][0][0]);
#pragma unroll
  for (int k = 0; k < 3; ++k) {
    float4 a = r[k], b = r[3 + k];
    s[4 * k + 0] = a.x + b.x;
    s[4 * k + 1] = a.y + b.y;
    s[4 * k + 2] = a.z + b.z;
    s[4 * k + 3] = a.w + b.w;
  }
}

// ---------------------------------------------------------------------------
// Main: one block per (b,f), 128 threads (2 waves), 8 frames/thread as
// 4x v2f pairs. Round-10 structure; accumulate loops forced to v_pk_*_f32.
// ---------------------------------------------------------------------------
__global__ __launch_bounds__(128, 2) void k_main(const float* __restrict__ Xr,
                                                 const float* __restrict__ Xi,
                                                 float* __restrict__ out, int nout) {
  const int blk = blockIdx.x;
  const int b = blk / NF, f = blk % NF;
  const int tid = threadIdx.x;            // 0..127
  const int lane = tid & 63, wvid = tid >> 6;
  const float invN = 1.f / (float)NFR;

  __shared__ float red[2][2][12];
  __shared__ float Wre[NC][NC], Wim[NC][NC];
  __shared__ float abc[8];

  v2f xcr[NC][4], xci[NC][4];
  int rowbase[NC];
#pragma unroll
  for (int c = 0; c < NC; ++c) {
    rowbase[c] = ((b * NC + c) * NF + f) * NFR;
    const float4* pr = reinterpret_cast<const float4*>(Xr + rowbase[c]);
    const float4* pi = reinterpret_cast<const float4*>(Xi + rowbase[c]);
    float4 a0 = pr[2 * tid], a1 = pr[2 * tid + 1];
    float4 b0 = pi[2 * tid], b1 = pi[2 * tid + 1];
    xcr[c][0] = (v2f){a0.x, a0.y}; xcr[c][1] = (v2f){a0.z, a0.w};
    xcr[c][2] = (v2f){a1.x, a1.y}; xcr[c][3] = (v2f){a1.z, a1.w};
    xci[c][0] = (v2f){b0.x, b0.y}; xci[c][1] = (v2f){b0.z, b0.w};
    xci[c][2] = (v2f){b1.x, b1.y}; xci[c][3] = (v2f){b1.z, b1.w};
  }
  if (tid < 16) {
    Wre[tid >> 2][tid & 3] = ((tid >> 2) == (tid & 3)) ? 1.f : 0.f;
    Wim[tid >> 2][tid & 3] = 0.f;
  }
  // W-init visibility to thread 0: ordered by the first sweep's barrier.

  v2f w2[NC][4];
  int buf = 0;

  for (int e = 0; e < 3; ++e) {
    // ---- per-epoch weights: w = g * rcp(max(2*sqrt(S/P), eps)) ----
#pragma unroll
    for (int c = 0; c < NC; ++c) {
      float g = g_gP[e * 32 + b * NC + c];
      float P = g_gP[e * 32 + 16 + b * NC + c];
      float sc = __builtin_amdgcn_rcpf(P);
      const float4* ps = reinterpret_cast<const float4*>(g_S + (b * NC + c) * NFR);
      float4 S0 = ps[2 * tid], S1 = ps[2 * tid + 1];
      float sv[8] = {S0.x, S0.y, S0.z, S0.w, S1.x, S1.y, S1.z, S1.w};
      float wv[8];
#pragma unroll
      for (int j = 0; j < 8; ++j)
        wv[j] = g * __builtin_amdgcn_rcpf(fmaxf(2.f * __builtin_amdgcn_sqrtf(sv[j] * sc), EPS_MODEL));
#pragma unroll
      for (int h = 0; h < 4; ++h) w2[c][h] = (v2f){wv[2 * h], wv[2 * h + 1]};
    }

    // ================= type-1 sweeps =================
    for (int src = 0; src < NC; ++src) {
      v2f p2[12];
#pragma unroll
      for (int k = 0; k < 12; ++k) p2[k] = (v2f){0.f, 0.f};
#pragma unroll
      for (int h = 0; h < 4; ++h) {
        v2f xsr = xcr[src][h], xsi = xci[src][h];
        v2f msq = pk_fma(xsi, xsi, pk_mul(xsr, xsr));
#pragma unroll
        for (int c = 0; c < NC; ++c) {
          v2f wv = w2[c][h];
          v2f t1 = pk_fma(xci[c][h], xsi, pk_mul(xcr[c][h], xsr));
          p2[c] = pk_fma(wv, t1, p2[c]);
          v2f t2 = pk_fnma(xcr[c][h], xsi, pk_mul(xci[c][h], xsr));
          p2[4 + c] = pk_fma(wv, t2, p2[4 + c]);
          p2[8 + c] = pk_fma(wv, msq, p2[8 + c]);
        }
      }
      float p[12];
#pragma unroll
      for (int k = 0; k < 12; ++k) p[k] = p2[k].x + p2[k].y;
      float s12[12];
      block_reduce12(p, red, buf, lane, wvid, s12);
      buf ^= 1;

      float vr[NC], vi[NC];
#pragma unroll
      for (int c = 0; c < NC; ++c) {
        float den = fmaxf(s12[8 + c] * invN, EPSV);
        if (c == src) {
          vr[c] = 1.f - __builtin_amdgcn_rsqf(den);
          vi[c] = 0.f;
        } else {
          float sc = invN * __builtin_amdgcn_rcpf(den);
          vr[c] = s12[c] * sc;
          vi[c] = s12[4 + c] * sc;
        }
      }
#pragma unroll
      for (int h = 0; h < 4; ++h) {
        v2f xsr = xcr[src][h], xsi = xci[src][h];
#pragma unroll
        for (int c = 0; c < NC; ++c) {
          xcr[c][h] -= xsr * vr[c] - xsi * vi[c];
          xci[c][h] -= xsi * vr[c] + xsr * vi[c];
        }
      }
      if (tid == 0) {
#pragma unroll
        for (int jj = 0; jj < NC; ++jj) {
          float wsr = Wre[src][jj], wsi = Wim[src][jj];
#pragma unroll
          for (int c = 0; c < NC; ++c) {
            Wre[c][jj] -= vr[c] * wsr - vi[c] * wsi;
            Wim[c][jj] -= vr[c] * wsi + vi[c] * wsr;
          }
        }
      }
    }

    // ================= type-2 sweeps =================
    for (int src = 0; src < NC; ++src) {
      const float4* pr = reinterpret_cast<const float4*>(Xr + rowbase[src]);
      const float4* pi = reinterpret_cast<const float4*>(Xi + rowbase[src]);
      // 9-frame window [8t-3 .. 8t+5] of ORIGINAL X serves both taps.
      float4 A4r = make_float4(0.f, 0.f, 0.f, 0.f), A4i = A4r;
      if (tid > 0) { A4r = pr[2 * tid - 1]; A4i = pi[2 * tid - 1]; }
      float4 B4r = pr[2 * tid], B4i = pi[2 * tid];
      float4 C4r = pr[2 * tid + 1], C4i = pi[2 * tid + 1];
      float wr[9] = {A4r.y, A4r.z, A4r.w, B4r.x, B4r.y, B4r.z, B4r.w, C4r.x, C4r.y};
      float wi[9] = {A4i.y, A4i.z, A4i.w, B4i.x, B4i.y, B4i.z, B4i.w, C4i.x, C4i.y};
      for (int tap = 0; tap < 2; ++tap) {
        v2f xs_r[4], xs_i[4];
#pragma unroll
        for (int h = 0; h < 4; ++h) {
          xs_r[h] = (v2f){wr[tap + 2 * h], wr[tap + 2 * h + 1]};
          xs_i[h] = (v2f){wi[tap + 2 * h], wi[tap + 2 * h + 1]};
        }
        v2f p2[12];
#pragma unroll
        for (int k = 0; k < 12; ++k) p2[k] = (v2f){0.f, 0.f};
#pragma unroll
        for (int h = 0; h < 4; ++h) {
          v2f xsr = xs_r[h], xsi = xs_i[h];
          v2f msq = pk_fma(xsi, xsi, pk_mul(xsr, xsr));
#pragma unroll
          for (int c = 0; c < NC; ++c) {
            v2f wv = w2[c][h];
            v2f t1 = pk_fma(xci[c][h], xsi, pk_mul(xcr[c][h], xsr));
            p2[c] = pk_fma(wv, t1, p2[c]);
            v2f t2 = pk_fnma(xcr[c][h], xsi, pk_mul(xci[c][h], xsr));
            p2[4 + c] = pk_fma(wv, t2, p2[4 + c]);
            p2[8 + c] = pk_fma(wv, msq, p2[8 + c]);
          }
        }
        float p[12];
#pragma unroll
        for (int k = 0; k < 12; ++k) p[k] = p2[k].x + p2[k].y;
        float s12[12];
        block_reduce12(p, red, buf, lane, wvid, s12);
        buf ^= 1;

        float vr[NC], vi[NC];
#pragma unroll
        for (int c = 0; c < NC; ++c) {
          float den = fmaxf(s12[8 + c], EPSV);  // SUM, not mean
          float sc = invN * __builtin_amdgcn_rcpf(den);
          vr[c] = s12[c] * sc;
          vi[c] = s12[4 + c] * sc;
        }
#pragma unroll
        for (int h = 0; h < 4; ++h) {
          v2f xsr = xs_r[h], xsi = xs_i[h];
#pragma unroll
          for (int c = 0; c < NC; ++c) {
            xcr[c][h] -= xsr * vr[c] - xsi * vi[c];
            xci[c][h] -= xsi * vr[c] + xsr * vi[c];
          }
        }
      }
    }
  }  // epochs

  // ---- solve W^T a = e1 (4x4 complex, partial pivoting), A[i][j] = W[j][i] ----
  __syncthreads();
  if (tid == 0) {
    float Ar[4][4], Ai[4][4];
    float br[4] = {1.f, 0.f, 0.f, 0.f}, bi[4] = {0.f, 0.f, 0.f, 0.f};
#pragma unroll
    for (int i = 0; i < 4; ++i)
#pragma unroll
      for (int j = 0; j < 4; ++j) {
        Ar[i][j] = Wre[j][i];
        Ai[i][j] = Wim[j][i];
      }
    for (int k = 0; k < 4; ++k) {
      int piv = k;
      float best = Ar[k][k] * Ar[k][k] + Ai[k][k] * Ai[k][k];
      for (int i = k + 1; i < 4; ++i) {
        float m = Ar[i][k] * Ar[i][k] + Ai[i][k] * Ai[i][k];
        if (m > best) { best = m; piv = i; }
      }
      if (piv != k) {
        for (int j = 0; j < 4; ++j) {
          float t = Ar[k][j]; Ar[k][j] = Ar[piv][j]; Ar[piv][j] = t;
          t = Ai[k][j]; Ai[k][j] = Ai[piv][j]; Ai[piv][j] = t;
        }
        float t = br[k]; br[k] = br[piv]; br[piv] = t;
        t = bi[k]; bi[k] = bi[piv]; bi[piv] = t;
      }
      float dr = Ar[k][k], di = Ai[k][k];
      float inv = 1.f / (dr * dr + di * di);
      for (int i = k + 1; i < 4; ++i) {
        float fr = (Ar[i][k] * dr + Ai[i][k] * di) * inv;
        float fi = (Ai[i][k] * dr - Ar[i][k] * di) * inv;
        for (int j = k; j < 4; ++j) {
          Ar[i][j] -= fr * Ar[k][j] - fi * Ai[k][j];
          Ai[i][j] -= fr * Ai[k][j] + fi * Ar[k][j];
        }
        br[i] -= fr * br[k] - fi * bi[k];
        bi[i] -= fr * bi[k] + fi * br[k];
      }
    }
    float ar[4], ai[4];
    for (int k = 3; k >= 0; --k) {
      float sr = br[k], si = bi[k];
      for (int j = k + 1; j < 4; ++j) {
        sr -= Ar[k][j] * ar[j] - Ai[k][j] * ai[j];
        si -= Ar[k][j] * ai[j] + Ai[k][j] * ar[j];
      }
      float dr = Ar[k][k], di = Ai[k][k];
      float inv = 1.f / (dr * dr + di * di);
      ar[k] = (sr * dr + si * di) * inv;
      ai[k] = (si * dr - sr * di) * inv;
    }
#pragma unroll
    for (int c = 0; c < 4; ++c) { abc[c] = ar[c]; abc[4 + c] = ai[c]; }
  }
  __syncthreads();

  // ---- output: real(Xc * a), 2x float4 per (c, thread), bounds-guarded ----
#pragma unroll
  for (int c = 0; c < NC; ++c) {
    float ar = abc[c], ai2 = abc[4 + c];
    if (rowbase[c] + 8 * tid + 7 < nout) {
      float4* po = reinterpret_cast<float4*>(out + rowbase[c]);
      v2f o0 = xcr[c][0] * ar - xci[c][0] * ai2;
      v2f o1 = xcr[c][1] * ar - xci[c][1] * ai2;
      v2f o2 = xcr[c][2] * ar - xci[c][2] * ai2;
      v2f o3 = xcr[c][3] * ar - xci[c][3] * ai2;
      po[2 * tid]     = make_float4(o0.x, o0.y, o1.x, o1.y);
      po[2 * tid + 1] = make_float4(o2.x, o2.y, o3.x, o3.y);
    }
  }
}

// ---------------------------------------------------------------------------
extern "C" void kernel_launch(void* const* d_in, const int* in_sizes, int n_in,
                              void* d_out, int out_size, void* d_ws, size_t ws_size,
                              hipStream_t stream) {
  const float* Xr = (const float*)d_in[0];
  const float* Xi = (const float*)d_in[1];
  float* out = (float*)d_out;

  dim3 g1(16, NCHUNK);
  k_colsum<<<g1, 256, 0, stream>>>(Xr, Xi);
  k_redgp<<<16, 256, 0, stream>>>();
  k_main<<<NB * NF, 128, 0, stream>>>(Xr, Xi, out, out_size);
}